// Round 8
// baseline (126.094 us; speedup 1.0000x reference)
//
#include <hip/hip_runtime.h>

#define HH 16
#define TT 4096
#define DD 64

typedef __attribute__((ext_vector_type(4))) _Float16 half4;
typedef __attribute__((ext_vector_type(4))) float float4v;

// One block = 32 q rows of one head; 4 waves. Wave w: row sub-block (w&1)*16,
// tile parity (w>>1): pair A (waves 0,1) computes even 64-key tiles, pair B
// (waves 2,3) odd tiles; all waves cooperatively stage every tile (dbuf LDS,
// single barrier per tile). End: merge pair partials (m,l,acc) through LDS.
// Grid 2048 > residency (~5 blocks/CU by LDS) -> hardware queue smooths the
// segment-length imbalance; split-K halves the per-unit chain length.
// LDS swizzle (R6/R7-proven, quarter-wave conflict-free):
//   phys(row, o8) = row*128 + 16*((o8>>1)^(row&7)) + 8*((o8&1)^((row>>3)&1))
__global__ __launch_bounds__(256, 4) void pa_fwd(
    const float* __restrict__ qg, const float* __restrict__ kg,
    const float* __restrict__ vg, const int* __restrict__ cu,
    float* __restrict__ outg)
{
    __shared__ __align__(16) _Float16 Kl[2][64 * 64];
    __shared__ __align__(16) _Float16 Vl[2][64 * 64];

    const int tid  = threadIdx.x;
    const int lane = tid & 63;
    const int wave = tid >> 6;      // 0..3
    const int lr   = lane & 15;
    const int lg   = lane >> 4;
    const int rsub = wave & 1;      // 16-row sub-block within the 32 q rows
    const int par  = wave >> 1;     // owned tile parity

    // XCD swizzle: grid 2048 = 8 XCD x 256 contiguous work items
    const int bswz = ((int)blockIdx.x & 7) * 256 + ((int)blockIdx.x >> 3);
    const int h    = bswz >> 7;            // 0..15
    const int qb0  = (bswz & 127) << 5;    // 32 q rows per block
    const int q    = qb0 + rsub * 16 + lr;

    // per-row segment bounds (searchsorted semantics)
    int s = 0;
    while (cu[s + 1] <= q) ++s;
    const int lo = cu[s], hi = cu[s + 1];

    // block-level staging range
    int sb = 0;
    while (cu[sb + 1] <= qb0) ++sb;
    const int blo = cu[sb];
    while (cu[sb + 1] <= qb0 + 31) ++sb;
    const int bhi = cu[sb + 1];

    const int wlo = __shfl(lo, 0);    // wave min key
    const int whi = __shfl(hi, 15);   // wave max key
    const int mlo = __shfl(lo, 15);   // max lo over wave rows
    const int mhi = __shfl(hi, 0);    // min hi over wave rows

    // Q fragment (B operand), pre-scaled by 1/sqrt(64)
    const float* qrow = qg + ((size_t)h * TT + q) * DD;
    half4 qf[4];
#pragma unroll
    for (int ds = 0; ds < 4; ++ds) {
        float4v t4 = *(const float4v*)(qrow + ds * 16 + lg * 4);
#pragma unroll
        for (int j = 0; j < 4; ++j) qf[ds][j] = (_Float16)(t4[j] * 0.125f);
    }

    const float* kh_ = kg + (size_t)h * TT * DD;
    const float* vh_ = vg + (size_t)h * TT * DD;

    // staging assignments
    const int srow = tid >> 2;          // K key row 0..63
    const int sch  = (tid & 3) << 4;    // K float chunk base (16 floats)
    const int vd   = tid & 63;          // Vt row (d column of V)

    // swizzled write offsets (bytes, loop-invariant)
    unsigned kwr[4], vwr[4];
#pragma unroll
    for (int i = 0; i < 4; ++i) {
        const int ko8 = (tid & 3) * 4 + i;
        kwr[i] = (unsigned)(srow * 128 + 16 * ((ko8 >> 1) ^ (srow & 7)) +
                            8 * ((ko8 & 1) ^ ((srow >> 3) & 1)));
        const int vo8 = wave * 4 + i;
        vwr[i] = (unsigned)(vd * 128 + 16 * ((vo8 >> 1) ^ (vd & 7)) +
                            8 * ((vo8 & 1) ^ ((vd >> 3) & 1)));
    }
    // swizzled fragment-read bases (bytes): rbase[x] + y*2048
    unsigned rbase[4];
#pragma unroll
    for (int i = 0; i < 4; ++i)
        rbase[i] = (unsigned)(lr * 128 + 16 * (((2 * i + (lg >> 1))) ^ (lr & 7)) +
                              8 * ((lg & 1) ^ ((lr >> 3) & 1)));

    // prefetch registers
    float4v kq[4];
    float vv[16];

    const int t0k = blo & ~63;
#define ISSUE(KT)                                                              \
    {                                                                          \
        int krow = (KT) + srow; if (krow > TT - 1) krow = TT - 1;              \
        const float4v* kp = (const float4v*)(kh_ + (size_t)krow * DD + sch);   \
        kq[0] = kp[0]; kq[1] = kp[1]; kq[2] = kp[2]; kq[3] = kp[3];            \
        _Pragma("unroll")                                                      \
        for (int c = 0; c < 16; ++c) {                                         \
            int vrow = (KT) + wave * 16 + c; if (vrow > TT - 1) vrow = TT - 1; \
            vv[c] = vh_[(size_t)vrow * DD + vd];                               \
        }                                                                      \
    }

    ISSUE(t0k);

    float4v acc[4];
#pragma unroll
    for (int dt = 0; dt < 4; ++dt) acc[dt] = (float4v){0.f, 0.f, 0.f, 0.f};
    float m_run = -1e30f, lsum = 0.f;

    int cur = 0;
    for (int kt = t0k; kt < bhi; kt += 64) {
        // ---- pack + write LDS buf[cur] ----
        {
            char* Kb = (char*)Kl[cur];
            char* Vb = (char*)Vl[cur];
#pragma unroll
            for (int i = 0; i < 4; ++i) {
                half4 hk;
#pragma unroll
                for (int m = 0; m < 4; ++m) hk[m] = (_Float16)kq[i][m];
                *(half4*)(Kb + kwr[i]) = hk;
            }
#pragma unroll
            for (int i = 0; i < 4; ++i) {
                half4 hv;
#pragma unroll
                for (int m = 0; m < 4; ++m) hv[m] = (_Float16)vv[4 * i + m];
                *(half4*)(Vb + vwr[i]) = hv;
            }
        }
        __syncthreads();   // the only barrier per tile

        if (kt + 64 < bhi) ISSUE(kt + 64);   // wave-uniform

        if ((((kt >> 6) & 1) == par) && !(kt + 64 <= wlo || kt >= whi)) {
            const char* Kb = (const char*)Kl[cur];
            const char* Vb = (const char*)Vl[cur];

            // ---- QK^T: St[key][q], 4 x 16-key quarters ----
            float st[4][4];
            const bool fullv = (kt >= mlo) && (kt + 64 <= mhi);  // wave-uniform
            __builtin_amdgcn_s_setprio(1);
#pragma unroll
            for (int t = 0; t < 4; ++t) {
                float4v sa = (float4v){0.f, 0.f, 0.f, 0.f};
#pragma unroll
                for (int ds = 0; ds < 4; ++ds) {
                    half4 kf = *(const half4*)(Kb + rbase[ds] + t * 2048);
                    sa = __builtin_amdgcn_mfma_f32_16x16x16f16(kf, qf[ds], sa, 0, 0, 0);
                }
                if (fullv) {
#pragma unroll
                    for (int j = 0; j < 4; ++j) st[t][j] = sa[j];
                } else {
#pragma unroll
                    for (int j = 0; j < 4; ++j) {
                        const int key = kt + t * 16 + lg * 4 + j;
                        st[t][j] = (key >= lo && key < hi) ? sa[j] : -1e30f;
                    }
                }
            }
            __builtin_amdgcn_s_setprio(0);

            // ---- online softmax (per q row = lr; reduce over lg) ----
            float tx = -1e30f;
#pragma unroll
            for (int t = 0; t < 4; ++t)
#pragma unroll
                for (int j = 0; j < 4; ++j) tx = fmaxf(tx, st[t][j]);
            tx = fmaxf(tx, __shfl_xor(tx, 16));
            tx = fmaxf(tx, __shfl_xor(tx, 32));

            // defer-max: only rescale when some row's max grew past m+8
            if (__any(tx > m_run + 8.f)) {
                const float mn = fmaxf(m_run, tx);
                const float a  = __expf(m_run - mn);
                lsum *= a;
#pragma unroll
                for (int dt = 0; dt < 4; ++dt)
#pragma unroll
                    for (int j = 0; j < 4; ++j) acc[dt][j] *= a;
                m_run = mn;
            }
            // all-masked rows self-heal at the first real tile (a=0 wipes acc,l)

            half4 pb[4];
            float ps = 0.f;
#pragma unroll
            for (int t = 0; t < 4; ++t)
#pragma unroll
                for (int j = 0; j < 4; ++j) {
                    const float e = __expf(st[t][j] - m_run);  // bounded by e^8
                    ps += e;
                    pb[t][j] = (_Float16)e;
                }
            ps += __shfl_xor(ps, 16);
            ps += __shfl_xor(ps, 32);
            lsum += ps;

            // ---- PV: Ot += V^T * P^T ----
            __builtin_amdgcn_s_setprio(1);
#pragma unroll
            for (int t = 0; t < 4; ++t)
#pragma unroll
                for (int dt = 0; dt < 4; ++dt) {
                    half4 vf = *(const half4*)(Vb + rbase[t] + dt * 2048);
                    acc[dt] = __builtin_amdgcn_mfma_f32_16x16x16f16(vf, pb[t], acc[dt], 0, 0, 0);
                }
            __builtin_amdgcn_s_setprio(0);
        }
        cur ^= 1;
    }

    // ---- merge pair partials: B (waves 2,3) -> LDS -> A (waves 0,1) ----
    float* mb = (float*)(&Kl[0][0]);   // [2][16][64] f32 acc partials (8 KB)
    float* ml = (float*)(&Vl[0][0]);   // m: [0..31], l: [32..63]

    __syncthreads();   // all tile compute done before overwriting K/V LDS
    if (wave >= 2) {
#pragma unroll
        for (int dt = 0; dt < 4; ++dt)
            *(float4v*)(mb + (rsub * 16 + lr) * 64 + dt * 16 + lg * 4) = acc[dt];
        if (lg == 0) {
            ml[rsub * 16 + lr]      = m_run;
            ml[32 + rsub * 16 + lr] = lsum;
        }
    }
    __syncthreads();
    if (wave < 2) {
        const float mB = ml[rsub * 16 + lr];
        const float lB = ml[32 + rsub * 16 + lr];
        const float M  = fmaxf(m_run, mB);
        const float eA = __expf(m_run - M);
        const float eB = __expf(mB - M);
        const float inv = 1.0f / (eA * lsum + eB * lB);

        float* orow = outg + ((size_t)h * TT + q) * DD;
#pragma unroll
        for (int dt = 0; dt < 4; ++dt) {
            float4v aB = *(const float4v*)(mb + (rsub * 16 + lr) * 64 + dt * 16 + lg * 4);
            float4v o;
#pragma unroll
            for (int j = 0; j < 4; ++j)
                o[j] = (eA * acc[dt][j] + eB * aB[j]) * inv;
            *(float4v*)(orow + dt * 16 + lg * 4) = o;
        }
    }
#undef ISSUE
}

extern "C" void kernel_launch(void* const* d_in, const int* in_sizes, int n_in,
                              void* d_out, int out_size, void* d_ws, size_t ws_size,
                              hipStream_t stream) {
    const float* q  = (const float*)d_in[0];
    const float* k  = (const float*)d_in[1];
    const float* v  = (const float*)d_in[2];
    const int*   cu = (const int*)d_in[3];
    float* out = (float*)d_out;

    dim3 grid(HH * (TT / 32));   // 2048
    dim3 block(256);
    hipLaunchKernelGGL(pa_fwd, grid, block, 0, stream, q, k, v, cu, out);
}